// Round 9
// baseline (113.108 us; speedup 1.0000x reference)
//
#include <hip/hip_runtime.h>
#include <hip/hip_bf16.h>
#include <stdint.h>

typedef __bf16 bf16;
typedef __bf16 bf16x8 __attribute__((ext_vector_type(8)));
typedef __bf16 bf16x4 __attribute__((ext_vector_type(4)));
typedef __bf16 bf16x2 __attribute__((ext_vector_type(2)));
typedef float  f32x4  __attribute__((ext_vector_type(4)));
typedef float  f32x16 __attribute__((ext_vector_type(16)));
typedef unsigned int uint;

#define MFMA(a,b,c)   __builtin_amdgcn_mfma_f32_16x16x32_bf16((a),(b),(c),0,0,0)
#define MFMA32(a,b,c) __builtin_amdgcn_mfma_f32_32x32x16_bf16((a),(b),(c),0,0,0)
#define EXP2(x)       __builtin_amdgcn_exp2f(x)

__device__ __forceinline__ void gload_lds16(const void* g, void* lds) {
  __builtin_amdgcn_global_load_lds(
      (const __attribute__((address_space(1))) uint32_t*)g,
      (__attribute__((address_space(3))) uint32_t*)lds, 16, 0, 0);
}

__device__ __forceinline__ uint pk_bf16(float lo, float hi) {
  bf16x2 v; v[0] = (bf16)lo; v[1] = (bf16)hi;
  return __builtin_bit_cast(uint, v);
}

// ---------------- convert fp32 -> bf16 (x + 4 weights) ----------------
__global__ __launch_bounds__(256) void k_cvt(
    const float* __restrict__ x,
    const float* __restrict__ wq, const float* __restrict__ wk,
    const float* __restrict__ wv, const float* __restrict__ wo,
    bf16* __restrict__ xb, bf16* __restrict__ wqb, bf16* __restrict__ wkb,
    bf16* __restrict__ wvb, bf16* __restrict__ wob)
{
  int r = blockIdx.y;
  const float* s; bf16* d; int n;
  switch (r) {
    case 0: s = x;  d = xb;  n = 4194304; break;
    case 1: s = wq; d = wqb; n = 1048576; break;
    case 2: s = wk; d = wkb; n = 1048576; break;
    case 3: s = wv; d = wvb; n = 1048576; break;
    default: s = wo; d = wob; n = 1048576; break;
  }
  int i = (blockIdx.x * 256 + threadIdx.x) * 8;
  if (i >= n) return;
  const float4* sp = (const float4*)(s + i);
  float4 a = sp[0], b = sp[1];
  bf16x8 o;
  o[0]=(bf16)a.x; o[1]=(bf16)a.y; o[2]=(bf16)a.z; o[3]=(bf16)a.w;
  o[4]=(bf16)b.x; o[5]=(bf16)b.y; o[6]=(bf16)b.z; o[7]=(bf16)b.w;
  *(bf16x8*)(d + i) = o;
}

// ---------------- fused QKV projection GEMM (2-phase, BK=32 dbuf) -----------
__global__ __launch_bounds__(256, 2) void k_gemm_qkv(
    const bf16* __restrict__ A,
    const bf16* __restrict__ Wq, const bf16* __restrict__ Wk, const bf16* __restrict__ Wv,
    const float* __restrict__ bq, const float* __restrict__ bk, const float* __restrict__ bv,
    bf16* __restrict__ Qw, bf16* __restrict__ Kw, bf16* __restrict__ Vtw)
{
  __shared__ __align__(16) char As[2][8192];
  __shared__ __align__(16) char Bs[2][8192];
  int tid = threadIdx.x;
  int wv4 = tid >> 6, l = tid & 63, lo = l & 15, hi = l >> 4;
  int f = blockIdx.y * 32 + blockIdx.x;        // 0..767
  int xcd = f & 7, i8 = f >> 3;                // i8: 0..95
  int mt = xcd * 4 + (i8 & 3);                 // 0..31
  int ft = i8 >> 2;                            // 0..23
  int wsel = ft >> 3;
  const bf16* W = (wsel == 0) ? Wq : (wsel == 1) ? Wk : Wv;
  const float* bias = (wsel == 0) ? bq : (wsel == 1) ? bk : bv;
  int f0 = (ft & 7) * 128;
  const bf16* Ab = A + (size_t)mt * 128 * 1024;
  const bf16* Wb = W + (size_t)f0 * 1024;
  const bf16* Pa = (wsel < 2) ? Wb : Ab;   // first operand
  const bf16* Pb = (wsel < 2) ? Ab : Wb;   // second operand
  int wm = wv4 >> 1, wf = wv4 & 1;
  f32x4 acc[4][4];
  #pragma unroll
  for (int i = 0; i < 4; i++)
    #pragma unroll
    for (int j = 0; j < 4; j++) acc[i][j] = (f32x4){0.f, 0.f, 0.f, 0.f};

  #define STAGEG(t, bi) {                                              \
    int k0 = (t) * 32;                                                 \
    _Pragma("unroll")                                                  \
    for (int p = 0; p < 2; p++) {                                      \
      int sp = p * 256 + tid;                                          \
      int row = sp >> 2, s = sp & 3;                                   \
      int gc = k0 + 8 * (s ^ ((row >> 1) & 3));                        \
      gload_lds16(Pa + (size_t)row * 1024 + gc, As[bi] + sp * 16);     \
      gload_lds16(Pb + (size_t)row * 1024 + gc, Bs[bi] + sp * 16);     \
    } }

  STAGEG(0, 0);
  for (int t = 0; t < 32; ++t) {
    __syncthreads();
    if (t < 31) STAGEG(t + 1, (t + 1) & 1);
    const char* Ac = As[t & 1];
    const char* Bc = Bs[t & 1];
    bf16x8 af[4], bfr[4];
    #pragma unroll
    for (int ms = 0; ms < 4; ms++) {
      int row = wm * 64 + ms * 16 + lo;
      af[ms] = *(const bf16x8*)(Ac + row * 64 + 16 * (hi ^ ((row >> 1) & 3)));
    }
    #pragma unroll
    for (int fs = 0; fs < 4; fs++) {
      int row = wf * 64 + fs * 16 + lo;
      bfr[fs] = *(const bf16x8*)(Bc + row * 64 + 16 * (hi ^ ((row >> 1) & 3)));
    }
    __builtin_amdgcn_s_setprio(1);
    #pragma unroll
    for (int ms = 0; ms < 4; ms++)
      #pragma unroll
      for (int fs = 0; fs < 4; fs++)
        acc[ms][fs] = MFMA(af[ms], bfr[fs], acc[ms][fs]);
    __builtin_amdgcn_s_setprio(0);
  }
  #undef STAGEG

  if (wsel < 2) {
    bf16* Outp = (wsel == 0) ? Qw : Kw;
    float qs = (wsel == 0) ? 0.0450842199527801f : 1.0f;
    #pragma unroll
    for (int ms = 0; ms < 4; ms++) {
      int fl = f0 + wm * 64 + ms * 16 + hi * 4;
      int h = fl >> 6, dd = fl & 63;
      float4 b4 = *(const float4*)(bias + fl);
      #pragma unroll
      for (int fs = 0; fs < 4; fs++) {
        int m = mt * 128 + wf * 64 + fs * 16 + lo;
        int b = m >> 11, nn = m & 2047;
        bf16x4 w;
        #pragma unroll
        for (int r = 0; r < 4; r++)
          w[r] = (bf16)((acc[ms][fs][r] + ((const float*)&b4)[r]) * qs);
        *(bf16x4*)(Outp + (((size_t)(b * 16 + h) * 2048 + nn) * 64) + dd) = w;
      }
    }
  } else {
    #pragma unroll
    for (int fs = 0; fs < 4; fs++) {
      int fl = f0 + wf * 64 + fs * 16 + lo;
      int h = fl >> 6, dd = fl & 63;
      float bb = bias[fl];
      #pragma unroll
      for (int ms = 0; ms < 4; ms++) {
        int m = mt * 128 + wm * 64 + ms * 16 + hi * 4;
        int b = m >> 11, nn = m & 2047;
        bf16x4 w;
        #pragma unroll
        for (int r = 0; r < 4; r++) w[r] = (bf16)(acc[ms][fs][r] + bb);
        *(bf16x4*)(Vtw + (((size_t)(b * 16 + h) * 64 + dd) * 2048) + nn) = w;
      }
    }
  }
}

// ---------------- flash attention v5: KVBLK=128 two-chain ILP ----------------
// 4 waves x 32 q; grid (16,32) XCD-swizzled; 16 iters of 128 k each as two
// independent 64-wide chains (separate S and O accumulators) -> 2x chain ILP.
__global__ __launch_bounds__(256, 2) void k_attn(
    const bf16* __restrict__ Q, const bf16* __restrict__ K,
    const bf16* __restrict__ Vt, bf16* __restrict__ O)
{
  __shared__ __align__(16) char Ks[2][16384];   // [buf][128 k-rows][128B]
  __shared__ __align__(16) char Vs[2][16384];   // [buf][2 half][64 d-rows][128B]
  int tid = threadIdx.x;
  int wid = tid >> 6, l = tid & 63;
  int lq = l & 31, hi1 = l >> 5;
  int f = blockIdx.y * 16 + blockIdx.x;        // 0..511
  int xcd = f & 7, i8 = f >> 3;                // i8: 0..63
  int bh = xcd * 4 + (i8 & 3);                 // 0..31
  int qt = i8 >> 2;                            // 0..15
  int qg = qt * 128 + wid * 32 + lq;
  const bf16* Kb = K + (size_t)bh * 2048 * 64;
  const bf16* Vb = Vt + (size_t)bh * 64 * 2048;

  bf16x8 qf[4];
  const bf16* Qb = Q + ((size_t)bh * 2048 + qg) * 64 + hi1 * 8;
  #pragma unroll
  for (int c = 0; c < 4; c++) qf[c] = *(const bf16x8*)(Qb + 16 * c);

  f32x16 oA0, oA1, oB0, oB1, zz;
  #pragma unroll
  for (int r = 0; r < 16; r++) { zz[r] = 0.f; oA0[r] = 0.f; oA1[r] = 0.f; oB0[r] = 0.f; oB1[r] = 0.f; }
  float ls = 0.f;

  int srow = tid >> 3, slot = tid & 7;
  int swz = 16 * (slot ^ (srow & 7));
  int swk = lq & 7;
  uint4 k0r, k1r, k2r, k3r, v0r, v1r, v2r, v3r;
  #define STAGE(t) {                                                               \
    k0r = *(const uint4*)(Kb + (size_t)((t)*128 + srow) * 64 + slot * 8);          \
    k1r = *(const uint4*)(Kb + (size_t)((t)*128 + srow + 32) * 64 + slot * 8);     \
    k2r = *(const uint4*)(Kb + (size_t)((t)*128 + srow + 64) * 64 + slot * 8);     \
    k3r = *(const uint4*)(Kb + (size_t)((t)*128 + srow + 96) * 64 + slot * 8);     \
    v0r = *(const uint4*)(Vb + (size_t)srow * 2048 + (t)*128 + slot * 8);          \
    v1r = *(const uint4*)(Vb + (size_t)(srow + 32) * 2048 + (t)*128 + slot * 8);   \
    v2r = *(const uint4*)(Vb + (size_t)srow * 2048 + (t)*128 + 64 + slot * 8);     \
    v3r = *(const uint4*)(Vb + (size_t)(srow + 32) * 2048 + (t)*128 + 64 + slot * 8); }
  #define WRBUF(bi) {                                          \
    *(uint4*)(Ks[bi] + srow * 128 + swz)             = k0r;    \
    *(uint4*)(Ks[bi] + (srow + 32) * 128 + swz)      = k1r;    \
    *(uint4*)(Ks[bi] + (srow + 64) * 128 + swz)      = k2r;    \
    *(uint4*)(Ks[bi] + (srow + 96) * 128 + swz)      = k3r;    \
    *(uint4*)(Vs[bi] + srow * 128 + swz)             = v0r;    \
    *(uint4*)(Vs[bi] + (srow + 32) * 128 + swz)      = v1r;    \
    *(uint4*)(Vs[bi] + 8192 + srow * 128 + swz)      = v2r;    \
    *(uint4*)(Vs[bi] + 8192 + (srow + 32) * 128 + swz) = v3r; }
  #define EXPSUM(S, T0, T1, T2, T3)                     \
    _Pragma("unroll")                                   \
    for (int r = 0; r < 16; r += 4) {                   \
      S[r]   = EXP2(S[r]);   T0 += S[r];                \
      S[r+1] = EXP2(S[r+1]); T1 += S[r+1];              \
      S[r+2] = EXP2(S[r+2]); T2 += S[r+2];              \
      S[r+3] = EXP2(S[r+3]); T3 += S[r+3];              \
    }
  #define PACK(dst, plo, phi)                                                \
    _Pragma("unroll")                                                        \
    for (int m = 0; m < 2; m++) {                                            \
      uint a0 = pk_bf16(plo[8*m+0], plo[8*m+1]);                             \
      uint b0 = pk_bf16(plo[8*m+4], plo[8*m+5]);                             \
      asm volatile("v_permlane32_swap_b32 %0, %1" : "+v"(a0), "+v"(b0));     \
      uint a1 = pk_bf16(plo[8*m+2], plo[8*m+3]);                             \
      uint b1 = pk_bf16(plo[8*m+6], plo[8*m+7]);                             \
      asm volatile("v_permlane32_swap_b32 %0, %1" : "+v"(a1), "+v"(b1));     \
      dst[m] = (uint4){a0, a1, b0, b1};                                      \
      uint c0 = pk_bf16(phi[8*m+0], phi[8*m+1]);                             \
      uint d0 = pk_bf16(phi[8*m+4], phi[8*m+5]);                             \
      asm volatile("v_permlane32_swap_b32 %0, %1" : "+v"(c0), "+v"(d0));     \
      uint c1 = pk_bf16(phi[8*m+2], phi[8*m+3]);                             \
      uint d1 = pk_bf16(phi[8*m+6], phi[8*m+7]);                             \
      asm volatile("v_permlane32_swap_b32 %0, %1" : "+v"(c1), "+v"(d1));     \
      dst[2+m] = (uint4){c0, c1, d0, d1};                                    \
    }

  STAGE(0);
  WRBUF(0);
  STAGE(1);

  for (int t = 0; t < 16; ++t) {
    __syncthreads();
    const char* Kc = Ks[t & 1];
    const char* Vc = Vs[t & 1];

    // chain A: K fragments (k rows 0..63 of this pair)
    bf16x8 ka0[4], ka1[4];
    #pragma unroll
    for (int c = 0; c < 4; c++) {
      ka0[c] = *(const bf16x8*)(Kc + lq * 128 + 16 * ((2*c + hi1) ^ swk));
      ka1[c] = *(const bf16x8*)(Kc + (32 + lq) * 128 + 16 * ((2*c + hi1) ^ swk));
    }
    __builtin_amdgcn_s_setprio(1);
    f32x16 sA0 = MFMA32(ka0[0], qf[0], zz);
    f32x16 sA1 = MFMA32(ka1[0], qf[0], zz);
    #pragma unroll
    for (int c = 1; c < 4; c++) {
      sA0 = MFMA32(ka0[c], qf[c], sA0);
      sA1 = MFMA32(ka1[c], qf[c], sA1);
    }
    __builtin_amdgcn_s_setprio(0);

    // chain B: K fragments (k rows 64..127), issued early to hide LDS latency
    bf16x8 kb0[4], kb1[4];
    #pragma unroll
    for (int c = 0; c < 4; c++) {
      kb0[c] = *(const bf16x8*)(Kc + 8192 + lq * 128 + 16 * ((2*c + hi1) ^ swk));
      kb1[c] = *(const bf16x8*)(Kc + 8192 + (32 + lq) * 128 + 16 * ((2*c + hi1) ^ swk));
    }

    // softmax A (overlaps QK-B MFMA issue below)
    float a0 = 0.f, a1 = 0.f, a2 = 0.f, a3 = 0.f;
    EXPSUM(sA0, a0, a1, a2, a3);
    EXPSUM(sA1, a0, a1, a2, a3);

    __builtin_amdgcn_s_setprio(1);
    f32x16 sB0 = MFMA32(kb0[0], qf[0], zz);
    f32x16 sB1 = MFMA32(kb1[0], qf[0], zz);
    #pragma unroll
    for (int c = 1; c < 4; c++) {
      sB0 = MFMA32(kb0[c], qf[c], sB0);
      sB1 = MFMA32(kb1[c], qf[c], sB1);
    }
    __builtin_amdgcn_s_setprio(0);

    uint4 pfA[4];
    PACK(pfA, sA0, sA1);

    // V fragments chain A (issued before softmax B)
    bf16x8 va0[4], va1[4];
    #pragma unroll
    for (int c = 0; c < 4; c++) {
      va0[c] = *(const bf16x8*)(Vc + lq * 128 + 16 * ((2*c + hi1) ^ swk));
      va1[c] = *(const bf16x8*)(Vc + (32 + lq) * 128 + 16 * ((2*c + hi1) ^ swk));
    }

    // softmax B
    float b0 = 0.f, b1 = 0.f, b2 = 0.f, b3 = 0.f;
    EXPSUM(sB0, b0, b1, b2, b3);
    EXPSUM(sB1, b0, b1, b2, b3);
    ls += ((a0 + a1) + (a2 + a3)) + ((b0 + b1) + (b2 + b3));

    // PV chain A
    __builtin_amdgcn_s_setprio(1);
    #pragma unroll
    for (int c = 0; c < 4; c++) {
      bf16x8 pb = __builtin_bit_cast(bf16x8, pfA[c]);
      oA0 = MFMA32(va0[c], pb, oA0);
      oA1 = MFMA32(va1[c], pb, oA1);
    }
    __builtin_amdgcn_s_setprio(0);

    uint4 pfB[4];
    PACK(pfB, sB0, sB1);

    // PV chain B
    __builtin_amdgcn_s_setprio(1);
    #pragma unroll
    for (int c = 0; c < 4; c++) {
      bf16x8 pb = __builtin_bit_cast(bf16x8, pfB[c]);
      bf16x8 vb0 = *(const bf16x8*)(Vc + 8192 + lq * 128 + 16 * ((2*c + hi1) ^ swk));
      oB0 = MFMA32(vb0, pb, oB0);
      bf16x8 vb1 = *(const bf16x8*)(Vc + 8192 + (32 + lq) * 128 + 16 * ((2*c + hi1) ^ swk));
      oB1 = MFMA32(vb1, pb, oB1);
    }
    __builtin_amdgcn_s_setprio(0);

    if (t < 15) {
      WRBUF((t + 1) & 1);
      if (t < 14) STAGE(t + 2);
    }
  }
  #undef STAGE
  #undef WRBUF

  f32x16 o0 = oA0 + oB0;
  f32x16 o1 = oA1 + oB1;
  float lsum = ls + __shfl_xor(ls, 32);
  float inv = 1.0f / lsum;
  int b = bh >> 4, h = bh & 15;
  bf16* Ob = O + ((size_t)(b * 2048 + qg)) * 1024 + h * 64 + hi1 * 4;
  #pragma unroll
  for (int g = 0; g < 4; g++) {
    bf16x4 w0, w1;
    #pragma unroll
    for (int j = 0; j < 4; j++) {
      w0[j] = (bf16)(o0[4*g+j] * inv);
      w1[j] = (bf16)(o1[4*g+j] * inv);
    }
    *(bf16x4*)(Ob + g * 8)      = w0;
    *(bf16x4*)(Ob + 32 + g * 8) = w1;
  }
}

// ---------------- output projection GEMM (2-phase, 512 thr, W-first) --------
__global__ __launch_bounds__(512, 1) void k_gemm_out(
    const bf16* __restrict__ A,      // O [4096][1024] bf16
    const bf16* __restrict__ W,      // Wo bf16 [1024][1024]
    const float* __restrict__ bias,  // bo
    float* __restrict__ Cout)        // [4096][1024] fp32
{
  __shared__ __align__(16) char As[2][16384];
  __shared__ __align__(16) char Bs[2][16384];
  int tid = threadIdx.x;
  int wid = tid >> 6, l = tid & 63, lo = l & 15, hi = l >> 4;
  int f = blockIdx.y * 32 + blockIdx.x;        // 0..255
  int xcd = f & 7, i8 = f >> 3;                // i8: 0..31
  int mt = xcd * 4 + (i8 & 3);                 // 0..31
  int f0 = (i8 >> 2) * 128;                    // 0..7 tiles
  const bf16* Ab = A + (size_t)mt * 128 * 1024;
  const bf16* Wb = W + (size_t)f0 * 1024;
  int wm2 = wid >> 2, wf4 = wid & 3;   // 2M x 4F; per-wave out 64m x 32f
  f32x4 acc[2][4];                     // [f-sub][m-sub]
  #pragma unroll
  for (int i = 0; i < 2; i++)
    #pragma unroll
    for (int j = 0; j < 4; j++) acc[i][j] = (f32x4){0.f, 0.f, 0.f, 0.f};

  #define STAGEG(t, bi) {                                              \
    int k0 = (t) * 64;                                                 \
    _Pragma("unroll")                                                  \
    for (int p = 0; p < 2; p++) {                                      \
      int sp = p * 512 + tid;                                          \
      int row = sp >> 3, s = sp & 7;                                   \
      int gc = k0 + 8 * (s ^ (row & 7));                               \
      gload_lds16(Wb + (size_t)row * 1024 + gc, As[bi] + sp * 16);     \
      gload_lds16(Ab + (size_t)row * 1024 + gc, Bs[bi] + sp * 16);     \
    } }

  STAGEG(0, 0);
  for (int t = 0; t < 16; ++t) {
    __syncthreads();
    if (t < 15) STAGEG(t + 1, (t + 1) & 1);
    const char* Ac = As[t & 1];   // W tile (first operand)
    const char* Bc = Bs[t & 1];   // A tile (second operand)
    #pragma unroll
    for (int kk = 0; kk < 2; kk++) {
      bf16x8 wfr[2], afr[4];
      #pragma unroll
      for (int i = 0; i < 2; i++) {
        int row = wf4 * 32 + i * 16 + lo;
        wfr[i] = *(const bf16x8*)(Ac + row * 128 + 16 * ((kk * 4 + hi) ^ (row & 7)));
      }
      #pragma unroll
      for (int j = 0; j < 4; j++) {
        int row = wm2 * 64 + j * 16 + lo;
        afr[j] = *(const bf16x8*)(Bc + row * 128 + 16 * ((kk * 4 + hi) ^ (row & 7)));
      }
      __builtin_amdgcn_s_setprio(1);
      #pragma unroll
      for (int i = 0; i < 2; i++)
        #pragma unroll
        for (int j = 0; j < 4; j++)
          acc[i][j] = MFMA(wfr[i], afr[j], acc[i][j]);
      __builtin_amdgcn_s_setprio(0);
    }
  }
  #undef STAGEG

  #pragma unroll
  for (int i = 0; i < 2; i++) {
    int fl = f0 + wf4 * 32 + i * 16 + hi * 4;
    float4 b4 = *(const float4*)(bias + fl);
    #pragma unroll
    for (int j = 0; j < 4; j++) {
      int m = mt * 128 + wm2 * 64 + j * 16 + lo;
      float4 o;
      o.x = acc[i][j][0] + b4.x;
      o.y = acc[i][j][1] + b4.y;
      o.z = acc[i][j][2] + b4.z;
      o.w = acc[i][j][3] + b4.w;
      *(float4*)(Cout + (size_t)m * 1024 + fl) = o;
    }
  }
}

// ---------------- launch ----------------
extern "C" void kernel_launch(void* const* d_in, const int* in_sizes, int n_in,
                              void* d_out, int out_size, void* d_ws, size_t ws_size,
                              hipStream_t stream) {
  const float* x  = (const float*)d_in[0];
  const float* Wq = (const float*)d_in[1];
  const float* bq = (const float*)d_in[2];
  const float* Wk = (const float*)d_in[3];
  const float* bk = (const float*)d_in[4];
  const float* Wv = (const float*)d_in[5];
  const float* bv = (const float*)d_in[6];
  const float* Wo = (const float*)d_in[7];
  const float* bo = (const float*)d_in[8];
  float* out = (float*)d_out;
  char* ws = (char*)d_ws;

  bf16* xb  = (bf16*)(ws);
  bf16* wqb = (bf16*)(ws + 8388608);
  bf16* wkb = (bf16*)(ws + 10485760);
  bf16* wvb = (bf16*)(ws + 12582912);
  bf16* wob = (bf16*)(ws + 14680064);
  bf16* Qw  = (bf16*)(ws + 16777216);
  bf16* Kw  = (bf16*)(ws + 25165824);
  bf16* Vtw = (bf16*)(ws + 33554432);
  bf16* Ow  = (bf16*)(ws + 41943040);   // total 50331648 B

  k_cvt<<<dim3(2048, 5), 256, 0, stream>>>(x, Wq, Wk, Wv, Wo, xb, wqb, wkb, wvb, wob);
  k_gemm_qkv<<<dim3(32, 24), 256, 0, stream>>>(xb, wqb, wkb, wvb, bq, bk, bv, Qw, Kw, Vtw);
  k_attn<<<dim3(16, 32), 256, 0, stream>>>(Qw, Kw, Vtw, Ow);
  k_gemm_out<<<dim3(32, 8), 512, 0, stream>>>(Ow, wob, bo, out);
}

// Round 11
// 108.832 us; speedup vs baseline: 1.0393x; 1.0393x over previous
//
#include <hip/hip_runtime.h>
#include <hip/hip_bf16.h>
#include <stdint.h>

typedef __bf16 bf16;
typedef __bf16 bf16x8 __attribute__((ext_vector_type(8)));
typedef __bf16 bf16x4 __attribute__((ext_vector_type(4)));
typedef __bf16 bf16x2 __attribute__((ext_vector_type(2)));
typedef float  f32x4  __attribute__((ext_vector_type(4)));
typedef float  f32x16 __attribute__((ext_vector_type(16)));
typedef unsigned int uint;

#define MFMA(a,b,c)   __builtin_amdgcn_mfma_f32_16x16x32_bf16((a),(b),(c),0,0,0)
#define MFMA32(a,b,c) __builtin_amdgcn_mfma_f32_32x32x16_bf16((a),(b),(c),0,0,0)
#define EXP2(x)       __builtin_amdgcn_exp2f(x)

__device__ __forceinline__ void gload_lds16(const void* g, void* lds) {
  __builtin_amdgcn_global_load_lds(
      (const __attribute__((address_space(1))) uint32_t*)g,
      (__attribute__((address_space(3))) uint32_t*)lds, 16, 0, 0);
}

__device__ __forceinline__ uint pk_bf16(float lo, float hi) {
  bf16x2 v; v[0] = (bf16)lo; v[1] = (bf16)hi;
  return __builtin_bit_cast(uint, v);
}

// ---------------- convert fp32 -> bf16 (x + 4 weights) ----------------
__global__ __launch_bounds__(256) void k_cvt(
    const float* __restrict__ x,
    const float* __restrict__ wq, const float* __restrict__ wk,
    const float* __restrict__ wv, const float* __restrict__ wo,
    bf16* __restrict__ xb, bf16* __restrict__ wqb, bf16* __restrict__ wkb,
    bf16* __restrict__ wvb, bf16* __restrict__ wob)
{
  int r = blockIdx.y;
  const float* s; bf16* d; int n;
  switch (r) {
    case 0: s = x;  d = xb;  n = 4194304; break;
    case 1: s = wq; d = wqb; n = 1048576; break;
    case 2: s = wk; d = wkb; n = 1048576; break;
    case 3: s = wv; d = wvb; n = 1048576; break;
    default: s = wo; d = wob; n = 1048576; break;
  }
  int i = (blockIdx.x * 256 + threadIdx.x) * 8;
  if (i >= n) return;
  const float4* sp = (const float4*)(s + i);
  float4 a = sp[0], b = sp[1];
  bf16x8 o;
  o[0]=(bf16)a.x; o[1]=(bf16)a.y; o[2]=(bf16)a.z; o[3]=(bf16)a.w;
  o[4]=(bf16)b.x; o[5]=(bf16)b.y; o[6]=(bf16)b.z; o[7]=(bf16)b.w;
  *(bf16x8*)(d + i) = o;
}

// ---------------- fused QKV projection GEMM (2-phase, BK=32 dbuf) -----------
__global__ __launch_bounds__(256, 2) void k_gemm_qkv(
    const bf16* __restrict__ A,
    const bf16* __restrict__ Wq, const bf16* __restrict__ Wk, const bf16* __restrict__ Wv,
    const float* __restrict__ bq, const float* __restrict__ bk, const float* __restrict__ bv,
    bf16* __restrict__ Qw, bf16* __restrict__ Kw, bf16* __restrict__ Vtw)
{
  __shared__ __align__(16) char As[2][8192];
  __shared__ __align__(16) char Bs[2][8192];
  int tid = threadIdx.x;
  int wv4 = tid >> 6, l = tid & 63, lo = l & 15, hi = l >> 4;
  int f = blockIdx.y * 32 + blockIdx.x;        // 0..767
  int xcd = f & 7, i8 = f >> 3;                // i8: 0..95
  int mt = xcd * 4 + (i8 & 3);                 // 0..31
  int ft = i8 >> 2;                            // 0..23
  int wsel = ft >> 3;
  const bf16* W = (wsel == 0) ? Wq : (wsel == 1) ? Wk : Wv;
  const float* bias = (wsel == 0) ? bq : (wsel == 1) ? bk : bv;
  int f0 = (ft & 7) * 128;
  const bf16* Ab = A + (size_t)mt * 128 * 1024;
  const bf16* Wb = W + (size_t)f0 * 1024;
  const bf16* Pa = (wsel < 2) ? Wb : Ab;   // first operand
  const bf16* Pb = (wsel < 2) ? Ab : Wb;   // second operand
  int wm = wv4 >> 1, wf = wv4 & 1;
  f32x4 acc[4][4];
  #pragma unroll
  for (int i = 0; i < 4; i++)
    #pragma unroll
    for (int j = 0; j < 4; j++) acc[i][j] = (f32x4){0.f, 0.f, 0.f, 0.f};

  #define STAGEG(t, bi) {                                              \
    int k0 = (t) * 32;                                                 \
    _Pragma("unroll")                                                  \
    for (int p = 0; p < 2; p++) {                                      \
      int sp = p * 256 + tid;                                          \
      int row = sp >> 2, s = sp & 3;                                   \
      int gc = k0 + 8 * (s ^ ((row >> 1) & 3));                        \
      gload_lds16(Pa + (size_t)row * 1024 + gc, As[bi] + sp * 16);     \
      gload_lds16(Pb + (size_t)row * 1024 + gc, Bs[bi] + sp * 16);     \
    } }

  STAGEG(0, 0);
  for (int t = 0; t < 32; ++t) {
    __syncthreads();
    if (t < 31) STAGEG(t + 1, (t + 1) & 1);
    const char* Ac = As[t & 1];
    const char* Bc = Bs[t & 1];
    bf16x8 af[4], bfr[4];
    #pragma unroll
    for (int ms = 0; ms < 4; ms++) {
      int row = wm * 64 + ms * 16 + lo;
      af[ms] = *(const bf16x8*)(Ac + row * 64 + 16 * (hi ^ ((row >> 1) & 3)));
    }
    #pragma unroll
    for (int fs = 0; fs < 4; fs++) {
      int row = wf * 64 + fs * 16 + lo;
      bfr[fs] = *(const bf16x8*)(Bc + row * 64 + 16 * (hi ^ ((row >> 1) & 3)));
    }
    __builtin_amdgcn_s_setprio(1);
    #pragma unroll
    for (int ms = 0; ms < 4; ms++)
      #pragma unroll
      for (int fs = 0; fs < 4; fs++)
        acc[ms][fs] = MFMA(af[ms], bfr[fs], acc[ms][fs]);
    __builtin_amdgcn_s_setprio(0);
  }
  #undef STAGEG

  if (wsel < 2) {
    bf16* Outp = (wsel == 0) ? Qw : Kw;
    float qs = (wsel == 0) ? 0.0450842199527801f : 1.0f;
    #pragma unroll
    for (int ms = 0; ms < 4; ms++) {
      int fl = f0 + wm * 64 + ms * 16 + hi * 4;
      int h = fl >> 6, dd = fl & 63;
      float4 b4 = *(const float4*)(bias + fl);
      #pragma unroll
      for (int fs = 0; fs < 4; fs++) {
        int m = mt * 128 + wf * 64 + fs * 16 + lo;
        int b = m >> 11, nn = m & 2047;
        bf16x4 w;
        #pragma unroll
        for (int r = 0; r < 4; r++)
          w[r] = (bf16)((acc[ms][fs][r] + ((const float*)&b4)[r]) * qs);
        *(bf16x4*)(Outp + (((size_t)(b * 16 + h) * 2048 + nn) * 64) + dd) = w;
      }
    }
  } else {
    #pragma unroll
    for (int fs = 0; fs < 4; fs++) {
      int fl = f0 + wf * 64 + fs * 16 + lo;
      int h = fl >> 6, dd = fl & 63;
      float bb = bias[fl];
      #pragma unroll
      for (int ms = 0; ms < 4; ms++) {
        int m = mt * 128 + wm * 64 + ms * 16 + hi * 4;
        int b = m >> 11, nn = m & 2047;
        bf16x4 w;
        #pragma unroll
        for (int r = 0; r < 4; r++) w[r] = (bf16)(acc[ms][fs][r] + bb);
        *(bf16x4*)(Vtw + (((size_t)(b * 16 + h) * 64 + dd) * 2048) + nn) = w;
      }
    }
  }
}

// ---------------- flash attention v6: 3-stage pipeline, triple-buffer LDS ----
// 4 waves x 32 q; grid (16,32) XCD-swizzled; per epoch: QK(t+1) MFMA issues
// first, softmax(t) VALU hides under it, then PV(t). One barrier per tile.
// S-sets ping-pong (sA/sB) via manual 2-body unroll -> all static indexing.
__global__ __launch_bounds__(256, 2) void k_attn(
    const bf16* __restrict__ Q, const bf16* __restrict__ K,
    const bf16* __restrict__ Vt, bf16* __restrict__ O)
{
  __shared__ __align__(16) char Ks[3][8192];
  __shared__ __align__(16) char Vs[3][8192];
  int tid = threadIdx.x;
  int wid = tid >> 6, l = tid & 63;
  int lq = l & 31, hi1 = l >> 5;
  int f = blockIdx.y * 16 + blockIdx.x;        // 0..511
  int xcd = f & 7, i8 = f >> 3;                // i8: 0..63
  int bh = xcd * 4 + (i8 & 3);                 // 0..31
  int qt = i8 >> 2;                            // 0..15
  int qg = qt * 128 + wid * 32 + lq;
  const bf16* Kb = K + (size_t)bh * 2048 * 64;
  const bf16* Vb = Vt + (size_t)bh * 64 * 2048;

  bf16x8 qf[4];
  const bf16* Qb = Q + ((size_t)bh * 2048 + qg) * 64 + hi1 * 8;
  #pragma unroll
  for (int c = 0; c < 4; c++) qf[c] = *(const bf16x8*)(Qb + 16 * c);

  f32x16 o0, o1, zz;
  #pragma unroll
  for (int r = 0; r < 16; r++) { zz[r] = 0.f; o0[r] = 0.f; o1[r] = 0.f; }
  float ls = 0.f;

  int srow = tid >> 3, slot = tid & 7;
  int swz = 16 * (slot ^ (srow & 7));
  int swk = lq & 7;
  uint4 k0r, k1r, v0r, v1r;
  #define STAGE(t) {                                                          \
    k0r = *(const uint4*)(Kb + (size_t)((t)*64 + srow) * 64 + slot * 8);      \
    k1r = *(const uint4*)(Kb + (size_t)((t)*64 + srow + 32) * 64 + slot * 8); \
    v0r = *(const uint4*)(Vb + (size_t)srow * 2048 + (t)*64 + slot * 8);      \
    v1r = *(const uint4*)(Vb + (size_t)(srow + 32) * 2048 + (t)*64 + slot * 8); }
  #define WRBUF(bi) {                                  \
    *(uint4*)(Ks[bi] + srow * 128 + swz)        = k0r; \
    *(uint4*)(Ks[bi] + (srow + 32) * 128 + swz) = k1r; \
    *(uint4*)(Vs[bi] + srow * 128 + swz)        = v0r; \
    *(uint4*)(Vs[bi] + (srow + 32) * 128 + swz) = v1r; }
  #define EXPSUM(S, T0, T1, T2, T3)                     \
    _Pragma("unroll")                                   \
    for (int r = 0; r < 16; r += 4) {                   \
      S[r]   = EXP2(S[r]);   T0 += S[r];                \
      S[r+1] = EXP2(S[r+1]); T1 += S[r+1];              \
      S[r+2] = EXP2(S[r+2]); T2 += S[r+2];              \
      S[r+3] = EXP2(S[r+3]); T3 += S[r+3];              \
    }
  #define PACK(dst, plo, phi)                                                \
    _Pragma("unroll")                                                        \
    for (int m = 0; m < 2; m++) {                                            \
      uint a0 = pk_bf16(plo[8*m+0], plo[8*m+1]);                             \
      uint b0 = pk_bf16(plo[8*m+4], plo[8*m+5]);                             \
      asm volatile("v_permlane32_swap_b32 %0, %1" : "+v"(a0), "+v"(b0));     \
      uint a1 = pk_bf16(plo[8*m+2], plo[8*m+3]);                             \
      uint b1 = pk_bf16(plo[8*m+6], plo[8*m+7]);                             \
      asm volatile("v_permlane32_swap_b32 %0, %1" : "+v"(a1), "+v"(b1));     \
      dst[m] = (uint4){a0, a1, b0, b1};                                      \
      uint c0 = pk_bf16(phi[8*m+0], phi[8*m+1]);                             \
      uint d0 = pk_bf16(phi[8*m+4], phi[8*m+5]);                             \
      asm volatile("v_permlane32_swap_b32 %0, %1" : "+v"(c0), "+v"(d0));     \
      uint c1 = pk_bf16(phi[8*m+2], phi[8*m+3]);                             \
      uint d1 = pk_bf16(phi[8*m+6], phi[8*m+7]);                             \
      asm volatile("v_permlane32_swap_b32 %0, %1" : "+v"(c1), "+v"(d1));     \
      dst[2+m] = (uint4){c0, c1, d0, d1};                                    \
    }
  // QK^T for one tile: read K frags from buf bi, produce S0/S1
  #define QKT(bi, S0, S1) {                                                  \
    bf16x8 kf0[4], kf1[4];                                                   \
    _Pragma("unroll")                                                        \
    for (int c = 0; c < 4; c++) {                                            \
      kf0[c] = *(const bf16x8*)(Ks[bi] + lq * 128 + 16 * ((2*c + hi1) ^ swk));        \
      kf1[c] = *(const bf16x8*)(Ks[bi] + (32 + lq) * 128 + 16 * ((2*c + hi1) ^ swk)); \
    }                                                                        \
    __builtin_amdgcn_s_setprio(1);                                           \
    S0 = MFMA32(kf0[0], qf[0], zz);                                          \
    S1 = MFMA32(kf1[0], qf[0], zz);                                          \
    _Pragma("unroll")                                                        \
    for (int c = 1; c < 4; c++) {                                            \
      S0 = MFMA32(kf0[c], qf[c], S0);                                        \
      S1 = MFMA32(kf1[c], qf[c], S1);                                        \
    }                                                                        \
    __builtin_amdgcn_s_setprio(0); }
  // softmax + pack + PV for tile in buf bi with scores S0/S1
  #define SMPV(bi, S0, S1) {                                                 \
    float e0 = 0.f, e1 = 0.f, e2 = 0.f, e3 = 0.f;                            \
    EXPSUM(S0, e0, e1, e2, e3);                                              \
    EXPSUM(S1, e0, e1, e2, e3);                                              \
    ls += (e0 + e1) + (e2 + e3);                                             \
    uint4 pf[4];                                                             \
    PACK(pf, S0, S1);                                                        \
    __builtin_amdgcn_s_setprio(1);                                           \
    _Pragma("unroll")                                                        \
    for (int c = 0; c < 4; c++) {                                            \
      bf16x8 pb = __builtin_bit_cast(bf16x8, pf[c]);                         \
      bf16x8 vf0 = *(const bf16x8*)(Vs[bi] + lq * 128 + 16 * ((2*c + hi1) ^ swk));        \
      o0 = MFMA32(vf0, pb, o0);                                              \
      bf16x8 vf1 = *(const bf16x8*)(Vs[bi] + (32 + lq) * 128 + 16 * ((2*c + hi1) ^ swk)); \
      o1 = MFMA32(vf1, pb, o1);                                              \
    }                                                                        \
    __builtin_amdgcn_s_setprio(0); }
  // one pipeline epoch: consume SC (tile t), produce SN (tile t+1)
  #define BODY(t, SC0, SC1, SN0, SN1) {                                      \
    __syncthreads();                                                         \
    if ((t) < 31) QKT(((t) + 1) % 3, SN0, SN1);                              \
    if ((t) < 30) WRBUF(((t) + 2) % 3);                                      \
    SMPV((t) % 3, SC0, SC1);                                                 \
    if ((t) < 29) STAGE((t) + 3); }

  // prologue: tiles 0,1 in LDS; tile-2 regs staged; QK(0) computed
  STAGE(0); WRBUF(0); STAGE(1);
  __syncthreads();
  WRBUF(1); STAGE(2);
  f32x16 sA0, sA1, sB0, sB1;
  QKT(0, sA0, sA1);

  for (int tt = 0; tt < 32; tt += 2) {
    BODY(tt,     sA0, sA1, sB0, sB1);
    BODY(tt + 1, sB0, sB1, sA0, sA1);
  }
  #undef STAGE
  #undef WRBUF
  #undef QKT
  #undef SMPV
  #undef BODY

  float lsum = ls + __shfl_xor(ls, 32);
  float inv = 1.0f / lsum;
  int b = bh >> 4, h = bh & 15;
  bf16* Ob = O + ((size_t)(b * 2048 + qg)) * 1024 + h * 64 + hi1 * 4;
  #pragma unroll
  for (int g = 0; g < 4; g++) {
    bf16x4 w0, w1;
    #pragma unroll
    for (int j = 0; j < 4; j++) {
      w0[j] = (bf16)(o0[4*g+j] * inv);
      w1[j] = (bf16)(o1[4*g+j] * inv);
    }
    *(bf16x4*)(Ob + g * 8)      = w0;
    *(bf16x4*)(Ob + 32 + g * 8) = w1;
  }
}

// ---------------- output projection GEMM (2-phase, 512 thr, W-first) --------
__global__ __launch_bounds__(512, 1) void k_gemm_out(
    const bf16* __restrict__ A,      // O [4096][1024] bf16
    const bf16* __restrict__ W,      // Wo bf16 [1024][1024]
    const float* __restrict__ bias,  // bo
    float* __restrict__ Cout)        // [4096][1024] fp32
{
  __shared__ __align__(16) char As[2][16384];
  __shared__ __align__(16) char Bs[2][16384];
  int tid = threadIdx.x;
  int wid = tid >> 6, l = tid & 63, lo = l & 15, hi = l >> 4;
  int f = blockIdx.y * 32 + blockIdx.x;        // 0..255
  int xcd = f & 7, i8 = f >> 3;                // i8: 0..31
  int mt = xcd * 4 + (i8 & 3);                 // 0..31
  int f0 = (i8 >> 2) * 128;                    // 0..7 tiles
  const bf16* Ab = A + (size_t)mt * 128 * 1024;
  const bf16* Wb = W + (size_t)f0 * 1024;
  int wm2 = wid >> 2, wf4 = wid & 3;   // 2M x 4F; per-wave out 64m x 32f
  f32x4 acc[2][4];                     // [f-sub][m-sub]
  #pragma unroll
  for (int i = 0; i < 2; i++)
    #pragma unroll
    for (int j = 0; j < 4; j++) acc[i][j] = (f32x4){0.f, 0.f, 0.f, 0.f};

  #define STAGEG(t, bi) {                                              \
    int k0 = (t) * 64;                                                 \
    _Pragma("unroll")                                                  \
    for (int p = 0; p < 2; p++) {                                      \
      int sp = p * 512 + tid;                                          \
      int row = sp >> 3, s = sp & 7;                                   \
      int gc = k0 + 8 * (s ^ (row & 7));                               \
      gload_lds16(Wb + (size_t)row * 1024 + gc, As[bi] + sp * 16);     \
      gload_lds16(Ab + (size_t)row * 1024 + gc, Bs[bi] + sp * 16);     \
    } }

  STAGEG(0, 0);
  for (int t = 0; t < 16; ++t) {
    __syncthreads();
    if (t < 15) STAGEG(t + 1, (t + 1) & 1);
    const char* Ac = As[t & 1];   // W tile (first operand)
    const char* Bc = Bs[t & 1];   // A tile (second operand)
    #pragma unroll
    for (int kk = 0; kk < 2; kk++) {
      bf16x8 wfr[2], afr[4];
      #pragma unroll
      for (int i = 0; i < 2; i++) {
        int row = wf4 * 32 + i * 16 + lo;
        wfr[i] = *(const bf16x8*)(Ac + row * 128 + 16 * ((kk * 4 + hi) ^ (row & 7)));
      }
      #pragma unroll
      for (int j = 0; j < 4; j++) {
        int row = wm2 * 64 + j * 16 + lo;
        afr[j] = *(const bf16x8*)(Bc + row * 128 + 16 * ((kk * 4 + hi) ^ (row & 7)));
      }
      __builtin_amdgcn_s_setprio(1);
      #pragma unroll
      for (int i = 0; i < 2; i++)
        #pragma unroll
        for (int j = 0; j < 4; j++)
          acc[i][j] = MFMA(wfr[i], afr[j], acc[i][j]);
      __builtin_amdgcn_s_setprio(0);
    }
  }
  #undef STAGEG

  #pragma unroll
  for (int i = 0; i < 2; i++) {
    int fl = f0 + wf4 * 32 + i * 16 + hi * 4;
    float4 b4 = *(const float4*)(bias + fl);
    #pragma unroll
    for (int j = 0; j < 4; j++) {
      int m = mt * 128 + wm2 * 64 + j * 16 + lo;
      float4 o;
      o.x = acc[i][j][0] + b4.x;
      o.y = acc[i][j][1] + b4.y;
      o.z = acc[i][j][2] + b4.z;
      o.w = acc[i][j][3] + b4.w;
      *(float4*)(Cout + (size_t)m * 1024 + fl) = o;
    }
  }
}

// ---------------- launch ----------------
extern "C" void kernel_launch(void* const* d_in, const int* in_sizes, int n_in,
                              void* d_out, int out_size, void* d_ws, size_t ws_size,
                              hipStream_t stream) {
  const float* x  = (const float*)d_in[0];
  const float* Wq = (const float*)d_in[1];
  const float* bq = (const float*)d_in[2];
  const float* Wk = (const float*)d_in[3];
  const float* bk = (const float*)d_in[4];
  const float* Wv = (const float*)d_in[5];
  const float* bv = (const float*)d_in[6];
  const float* Wo = (const float*)d_in[7];
  const float* bo = (const float*)d_in[8];
  float* out = (float*)d_out;
  char* ws = (char*)d_ws;

  bf16* xb  = (bf16*)(ws);
  bf16* wqb = (bf16*)(ws + 8388608);
  bf16* wkb = (bf16*)(ws + 10485760);
  bf16* wvb = (bf16*)(ws + 12582912);
  bf16* wob = (bf16*)(ws + 14680064);
  bf16* Qw  = (bf16*)(ws + 16777216);
  bf16* Kw  = (bf16*)(ws + 25165824);
  bf16* Vtw = (bf16*)(ws + 33554432);
  bf16* Ow  = (bf16*)(ws + 41943040);   // total 50331648 B

  k_cvt<<<dim3(2048, 5), 256, 0, stream>>>(x, Wq, Wk, Wv, Wo, xb, wqb, wkb, wvb, wob);
  k_gemm_qkv<<<dim3(32, 24), 256, 0, stream>>>(xb, wqb, wkb, wvb, bq, bk, bv, Qw, Kw, Vtw);
  k_attn<<<dim3(16, 32), 256, 0, stream>>>(Qw, Kw, Vtw, Ow);
  k_gemm_out<<<dim3(32, 8), 512, 0, stream>>>(Ow, wob, bo, out);
}

// Round 12
// 105.593 us; speedup vs baseline: 1.0712x; 1.0307x over previous
//
#include <hip/hip_runtime.h>
#include <hip/hip_bf16.h>
#include <stdint.h>

typedef __bf16 bf16;
typedef __bf16 bf16x8 __attribute__((ext_vector_type(8)));
typedef __bf16 bf16x4 __attribute__((ext_vector_type(4)));
typedef __bf16 bf16x2 __attribute__((ext_vector_type(2)));
typedef float  f32x4  __attribute__((ext_vector_type(4)));
typedef float  f32x16 __attribute__((ext_vector_type(16)));
typedef unsigned int uint;

#define MFMA(a,b,c)   __builtin_amdgcn_mfma_f32_16x16x32_bf16((a),(b),(c),0,0,0)
#define MFMA32(a,b,c) __builtin_amdgcn_mfma_f32_32x32x16_bf16((a),(b),(c),0,0,0)
#define EXP2(x)       __builtin_amdgcn_exp2f(x)

__device__ __forceinline__ void gload_lds16(const void* g, void* lds) {
  __builtin_amdgcn_global_load_lds(
      (const __attribute__((address_space(1))) uint32_t*)g,
      (__attribute__((address_space(3))) uint32_t*)lds, 16, 0, 0);
}

__device__ __forceinline__ uint pk_bf16(float lo, float hi) {
  bf16x2 v; v[0] = (bf16)lo; v[1] = (bf16)hi;
  return __builtin_bit_cast(uint, v);
}

// ---------------- convert fp32 -> bf16 (x + 4 weights) ----------------
__global__ __launch_bounds__(256) void k_cvt(
    const float* __restrict__ x,
    const float* __restrict__ wq, const float* __restrict__ wk,
    const float* __restrict__ wv, const float* __restrict__ wo,
    bf16* __restrict__ xb, bf16* __restrict__ wqb, bf16* __restrict__ wkb,
    bf16* __restrict__ wvb, bf16* __restrict__ wob)
{
  int r = blockIdx.y;
  const float* s; bf16* d; int n;
  switch (r) {
    case 0: s = x;  d = xb;  n = 4194304; break;
    case 1: s = wq; d = wqb; n = 1048576; break;
    case 2: s = wk; d = wkb; n = 1048576; break;
    case 3: s = wv; d = wvb; n = 1048576; break;
    default: s = wo; d = wob; n = 1048576; break;
  }
  int i = (blockIdx.x * 256 + threadIdx.x) * 8;
  if (i >= n) return;
  const float4* sp = (const float4*)(s + i);
  float4 a = sp[0], b = sp[1];
  bf16x8 o;
  o[0]=(bf16)a.x; o[1]=(bf16)a.y; o[2]=(bf16)a.z; o[3]=(bf16)a.w;
  o[4]=(bf16)b.x; o[5]=(bf16)b.y; o[6]=(bf16)b.z; o[7]=(bf16)b.w;
  *(bf16x8*)(d + i) = o;
}

// ---------------- fused QKV projection GEMM (2-phase, BK=32 dbuf) -----------
__global__ __launch_bounds__(256, 2) void k_gemm_qkv(
    const bf16* __restrict__ A,
    const bf16* __restrict__ Wq, const bf16* __restrict__ Wk, const bf16* __restrict__ Wv,
    const float* __restrict__ bq, const float* __restrict__ bk, const float* __restrict__ bv,
    bf16* __restrict__ Qw, bf16* __restrict__ Kw, bf16* __restrict__ Vtw)
{
  __shared__ __align__(16) char As[2][8192];
  __shared__ __align__(16) char Bs[2][8192];
  int tid = threadIdx.x;
  int wv4 = tid >> 6, l = tid & 63, lo = l & 15, hi = l >> 4;
  int f = blockIdx.y * 32 + blockIdx.x;        // 0..767
  int xcd = f & 7, i8 = f >> 3;                // i8: 0..95
  int mt = xcd * 4 + (i8 & 3);                 // 0..31
  int ft = i8 >> 2;                            // 0..23
  int wsel = ft >> 3;
  const bf16* W = (wsel == 0) ? Wq : (wsel == 1) ? Wk : Wv;
  const float* bias = (wsel == 0) ? bq : (wsel == 1) ? bk : bv;
  int f0 = (ft & 7) * 128;
  const bf16* Ab = A + (size_t)mt * 128 * 1024;
  const bf16* Wb = W + (size_t)f0 * 1024;
  const bf16* Pa = (wsel < 2) ? Wb : Ab;   // first operand
  const bf16* Pb = (wsel < 2) ? Ab : Wb;   // second operand
  int wm = wv4 >> 1, wf = wv4 & 1;
  f32x4 acc[4][4];
  #pragma unroll
  for (int i = 0; i < 4; i++)
    #pragma unroll
    for (int j = 0; j < 4; j++) acc[i][j] = (f32x4){0.f, 0.f, 0.f, 0.f};

  #define STAGEG(t, bi) {                                              \
    int k0 = (t) * 32;                                                 \
    _Pragma("unroll")                                                  \
    for (int p = 0; p < 2; p++) {                                      \
      int sp = p * 256 + tid;                                          \
      int row = sp >> 2, s = sp & 3;                                   \
      int gc = k0 + 8 * (s ^ ((row >> 1) & 3));                        \
      gload_lds16(Pa + (size_t)row * 1024 + gc, As[bi] + sp * 16);     \
      gload_lds16(Pb + (size_t)row * 1024 + gc, Bs[bi] + sp * 16);     \
    } }

  STAGEG(0, 0);
  for (int t = 0; t < 32; ++t) {
    __syncthreads();
    if (t < 31) STAGEG(t + 1, (t + 1) & 1);
    const char* Ac = As[t & 1];
    const char* Bc = Bs[t & 1];
    bf16x8 af[4], bfr[4];
    #pragma unroll
    for (int ms = 0; ms < 4; ms++) {
      int row = wm * 64 + ms * 16 + lo;
      af[ms] = *(const bf16x8*)(Ac + row * 64 + 16 * (hi ^ ((row >> 1) & 3)));
    }
    #pragma unroll
    for (int fs = 0; fs < 4; fs++) {
      int row = wf * 64 + fs * 16 + lo;
      bfr[fs] = *(const bf16x8*)(Bc + row * 64 + 16 * (hi ^ ((row >> 1) & 3)));
    }
    __builtin_amdgcn_s_setprio(1);
    #pragma unroll
    for (int ms = 0; ms < 4; ms++)
      #pragma unroll
      for (int fs = 0; fs < 4; fs++)
        acc[ms][fs] = MFMA(af[ms], bfr[fs], acc[ms][fs]);
    __builtin_amdgcn_s_setprio(0);
  }
  #undef STAGEG

  if (wsel < 2) {
    bf16* Outp = (wsel == 0) ? Qw : Kw;
    float qs = (wsel == 0) ? 0.0450842199527801f : 1.0f;
    #pragma unroll
    for (int ms = 0; ms < 4; ms++) {
      int fl = f0 + wm * 64 + ms * 16 + hi * 4;
      int h = fl >> 6, dd = fl & 63;
      float4 b4 = *(const float4*)(bias + fl);
      #pragma unroll
      for (int fs = 0; fs < 4; fs++) {
        int m = mt * 128 + wf * 64 + fs * 16 + lo;
        int b = m >> 11, nn = m & 2047;
        bf16x4 w;
        #pragma unroll
        for (int r = 0; r < 4; r++)
          w[r] = (bf16)((acc[ms][fs][r] + ((const float*)&b4)[r]) * qs);
        *(bf16x4*)(Outp + (((size_t)(b * 16 + h) * 2048 + nn) * 64) + dd) = w;
      }
    }
  } else {
    #pragma unroll
    for (int fs = 0; fs < 4; fs++) {
      int fl = f0 + wf * 64 + fs * 16 + lo;
      int h = fl >> 6, dd = fl & 63;
      float bb = bias[fl];
      #pragma unroll
      for (int ms = 0; ms < 4; ms++) {
        int m = mt * 128 + wm * 64 + ms * 16 + hi * 4;
        int b = m >> 11, nn = m & 2047;
        bf16x4 w;
        #pragma unroll
        for (int r = 0; r < 4; r++) w[r] = (bf16)(acc[ms][fs][r] + bb);
        *(bf16x4*)(Vtw + (((size_t)(b * 16 + h) * 64 + dd) * 2048) + nn) = w;
      }
    }
  }
}

// ---------------- flash attention v7: 2 tiles per barrier, 4-buffer LDS -----
// 4 waves x 32 q; grid (16,32) XCD-swizzled; per epoch (1 barrier): process
// tiles t,t+1 from bufs {B0,B1}, write staged tiles t+2,t+3 into {B2,B3},
// restage t+4,t+5. Static &-indexing, max-free exp2 softmax.
__global__ __launch_bounds__(256, 2) void k_attn(
    const bf16* __restrict__ Q, const bf16* __restrict__ K,
    const bf16* __restrict__ Vt, bf16* __restrict__ O)
{
  __shared__ __align__(16) char Ks[4][8192];
  __shared__ __align__(16) char Vs[4][8192];
  int tid = threadIdx.x;
  int wid = tid >> 6, l = tid & 63;
  int lq = l & 31, hi1 = l >> 5;
  int f = blockIdx.y * 16 + blockIdx.x;        // 0..511
  int xcd = f & 7, i8 = f >> 3;                // i8: 0..63
  int bh = xcd * 4 + (i8 & 3);                 // 0..31
  int qt = i8 >> 2;                            // 0..15
  int qg = qt * 128 + wid * 32 + lq;
  const bf16* Kb = K + (size_t)bh * 2048 * 64;
  const bf16* Vb = Vt + (size_t)bh * 64 * 2048;

  bf16x8 qf[4];
  const bf16* Qb = Q + ((size_t)bh * 2048 + qg) * 64 + hi1 * 8;
  #pragma unroll
  for (int c = 0; c < 4; c++) qf[c] = *(const bf16x8*)(Qb + 16 * c);

  f32x16 o0, o1, zz;
  #pragma unroll
  for (int r = 0; r < 16; r++) { zz[r] = 0.f; o0[r] = 0.f; o1[r] = 0.f; }
  float ls = 0.f;

  int srow = tid >> 3, slot = tid & 7;
  int swz = 16 * (slot ^ (srow & 7));
  int swk = lq & 7;
  uint4 xk0, xk1, xv0, xv1;    // staging set X (even tiles)
  uint4 yk0, yk1, yv0, yv1;    // staging set Y (odd tiles)
  #define STAGEX(t) {                                                          \
    xk0 = *(const uint4*)(Kb + (size_t)((t)*64 + srow) * 64 + slot * 8);       \
    xk1 = *(const uint4*)(Kb + (size_t)((t)*64 + srow + 32) * 64 + slot * 8);  \
    xv0 = *(const uint4*)(Vb + (size_t)srow * 2048 + (t)*64 + slot * 8);       \
    xv1 = *(const uint4*)(Vb + (size_t)(srow + 32) * 2048 + (t)*64 + slot * 8); }
  #define STAGEY(t) {                                                          \
    yk0 = *(const uint4*)(Kb + (size_t)((t)*64 + srow) * 64 + slot * 8);       \
    yk1 = *(const uint4*)(Kb + (size_t)((t)*64 + srow + 32) * 64 + slot * 8);  \
    yv0 = *(const uint4*)(Vb + (size_t)srow * 2048 + (t)*64 + slot * 8);       \
    yv1 = *(const uint4*)(Vb + (size_t)(srow + 32) * 2048 + (t)*64 + slot * 8); }
  #define WRX(bi) {                                     \
    *(uint4*)(Ks[bi] + srow * 128 + swz)        = xk0;  \
    *(uint4*)(Ks[bi] + (srow + 32) * 128 + swz) = xk1;  \
    *(uint4*)(Vs[bi] + srow * 128 + swz)        = xv0;  \
    *(uint4*)(Vs[bi] + (srow + 32) * 128 + swz) = xv1; }
  #define WRY(bi) {                                     \
    *(uint4*)(Ks[bi] + srow * 128 + swz)        = yk0;  \
    *(uint4*)(Ks[bi] + (srow + 32) * 128 + swz) = yk1;  \
    *(uint4*)(Vs[bi] + srow * 128 + swz)        = yv0;  \
    *(uint4*)(Vs[bi] + (srow + 32) * 128 + swz) = yv1; }
  #define EXPSUM(S, T0, T1, T2, T3)                     \
    _Pragma("unroll")                                   \
    for (int r = 0; r < 16; r += 4) {                   \
      S[r]   = EXP2(S[r]);   T0 += S[r];                \
      S[r+1] = EXP2(S[r+1]); T1 += S[r+1];              \
      S[r+2] = EXP2(S[r+2]); T2 += S[r+2];              \
      S[r+3] = EXP2(S[r+3]); T3 += S[r+3];              \
    }
  #define PACK(dst, plo, phi)                                                \
    _Pragma("unroll")                                                        \
    for (int m = 0; m < 2; m++) {                                            \
      uint a0 = pk_bf16(plo[8*m+0], plo[8*m+1]);                             \
      uint b0 = pk_bf16(plo[8*m+4], plo[8*m+5]);                             \
      asm volatile("v_permlane32_swap_b32 %0, %1" : "+v"(a0), "+v"(b0));     \
      uint a1 = pk_bf16(plo[8*m+2], plo[8*m+3]);                             \
      uint b1 = pk_bf16(plo[8*m+6], plo[8*m+7]);                             \
      asm volatile("v_permlane32_swap_b32 %0, %1" : "+v"(a1), "+v"(b1));     \
      dst[m] = (uint4){a0, a1, b0, b1};                                      \
      uint c0 = pk_bf16(phi[8*m+0], phi[8*m+1]);                             \
      uint d0 = pk_bf16(phi[8*m+4], phi[8*m+5]);                             \
      asm volatile("v_permlane32_swap_b32 %0, %1" : "+v"(c0), "+v"(d0));     \
      uint c1 = pk_bf16(phi[8*m+2], phi[8*m+3]);                             \
      uint d1 = pk_bf16(phi[8*m+6], phi[8*m+7]);                             \
      asm volatile("v_permlane32_swap_b32 %0, %1" : "+v"(c1), "+v"(d1));     \
      dst[2+m] = (uint4){c0, c1, d0, d1};                                    \
    }
  #define QKT(bi, S0, S1) {                                                  \
    bf16x8 kf0[4], kf1[4];                                                   \
    _Pragma("unroll")                                                        \
    for (int c = 0; c < 4; c++) {                                            \
      kf0[c] = *(const bf16x8*)(Ks[bi] + lq * 128 + 16 * ((2*c + hi1) ^ swk));        \
      kf1[c] = *(const bf16x8*)(Ks[bi] + (32 + lq) * 128 + 16 * ((2*c + hi1) ^ swk)); \
    }                                                                        \
    __builtin_amdgcn_s_setprio(1);                                           \
    S0 = MFMA32(kf0[0], qf[0], zz);                                          \
    S1 = MFMA32(kf1[0], qf[0], zz);                                          \
    _Pragma("unroll")                                                        \
    for (int c = 1; c < 4; c++) {                                            \
      S0 = MFMA32(kf0[c], qf[c], S0);                                        \
      S1 = MFMA32(kf1[c], qf[c], S1);                                        \
    }                                                                        \
    __builtin_amdgcn_s_setprio(0); }
  #define SMPV(bi, S0, S1) {                                                 \
    float e0 = 0.f, e1 = 0.f, e2 = 0.f, e3 = 0.f;                            \
    EXPSUM(S0, e0, e1, e2, e3);                                              \
    EXPSUM(S1, e0, e1, e2, e3);                                              \
    ls += (e0 + e1) + (e2 + e3);                                             \
    uint4 pf[4];                                                             \
    PACK(pf, S0, S1);                                                        \
    __builtin_amdgcn_s_setprio(1);                                           \
    _Pragma("unroll")                                                        \
    for (int c = 0; c < 4; c++) {                                            \
      bf16x8 pb = __builtin_bit_cast(bf16x8, pf[c]);                         \
      bf16x8 vf0 = *(const bf16x8*)(Vs[bi] + lq * 128 + 16 * ((2*c + hi1) ^ swk));        \
      o0 = MFMA32(vf0, pb, o0);                                              \
      bf16x8 vf1 = *(const bf16x8*)(Vs[bi] + (32 + lq) * 128 + 16 * ((2*c + hi1) ^ swk)); \
      o1 = MFMA32(vf1, pb, o1);                                              \
    }                                                                        \
    __builtin_amdgcn_s_setprio(0); }
  // one epoch = 2 tiles, 1 barrier. TT even. Reads B0,B1; writes B2,B3.
  #define EPOCH(TT, B0, B1, B2, B3) {                                        \
    __syncthreads();                                                         \
    f32x16 sA0, sA1, sB0, sB1;                                               \
    QKT(B0, sA0, sA1);                                                       \
    if ((TT) < 30) WRX(B2);                                                  \
    SMPV(B0, sA0, sA1);                                                      \
    QKT(B1, sB0, sB1);                                                       \
    if ((TT) < 30) WRY(B3);                                                  \
    SMPV(B1, sB0, sB1);                                                      \
    if ((TT) < 28) { STAGEX((TT) + 4); STAGEY((TT) + 5); } }

  // prologue: tiles 0,1 into LDS bufs 0,1; tiles 2,3 staged in regs
  STAGEX(0); STAGEY(1);
  WRX(0); WRY(1);
  STAGEX(2); STAGEY(3);

  for (int tt = 0; tt < 32; tt += 4) {
    EPOCH(tt,     0, 1, 2, 3);
    EPOCH(tt + 2, 2, 3, 0, 1);
  }
  #undef STAGEX
  #undef STAGEY
  #undef WRX
  #undef WRY
  #undef QKT
  #undef SMPV
  #undef EPOCH

  float lsum = ls + __shfl_xor(ls, 32);
  float inv = 1.0f / lsum;
  int b = bh >> 4, h = bh & 15;
  bf16* Ob = O + ((size_t)(b * 2048 + qg)) * 1024 + h * 64 + hi1 * 4;
  #pragma unroll
  for (int g = 0; g < 4; g++) {
    bf16x4 w0, w1;
    #pragma unroll
    for (int j = 0; j < 4; j++) {
      w0[j] = (bf16)(o0[4*g+j] * inv);
      w1[j] = (bf16)(o1[4*g+j] * inv);
    }
    *(bf16x4*)(Ob + g * 8)      = w0;
    *(bf16x4*)(Ob + 32 + g * 8) = w1;
  }
}

// ---------------- output projection GEMM (2-phase, 512 thr, W-first) --------
__global__ __launch_bounds__(512, 1) void k_gemm_out(
    const bf16* __restrict__ A,      // O [4096][1024] bf16
    const bf16* __restrict__ W,      // Wo bf16 [1024][1024]
    const float* __restrict__ bias,  // bo
    float* __restrict__ Cout)        // [4096][1024] fp32
{
  __shared__ __align__(16) char As[2][16384];
  __shared__ __align__(16) char Bs[2][16384];
  int tid = threadIdx.x;
  int wid = tid >> 6, l = tid & 63, lo = l & 15, hi = l >> 4;
  int f = blockIdx.y * 32 + blockIdx.x;        // 0..255
  int xcd = f & 7, i8 = f >> 3;                // i8: 0..31
  int mt = xcd * 4 + (i8 & 3);                 // 0..31
  int f0 = (i8 >> 2) * 128;                    // 0..7 tiles
  const bf16* Ab = A + (size_t)mt * 128 * 1024;
  const bf16* Wb = W + (size_t)f0 * 1024;
  int wm2 = wid >> 2, wf4 = wid & 3;   // 2M x 4F; per-wave out 64m x 32f
  f32x4 acc[2][4];                     // [f-sub][m-sub]
  #pragma unroll
  for (int i = 0; i < 2; i++)
    #pragma unroll
    for (int j = 0; j < 4; j++) acc[i][j] = (f32x4){0.f, 0.f, 0.f, 0.f};

  #define STAGEG(t, bi) {                                              \
    int k0 = (t) * 64;                                                 \
    _Pragma("unroll")                                                  \
    for (int p = 0; p < 2; p++) {                                      \
      int sp = p * 512 + tid;                                          \
      int row = sp >> 3, s = sp & 7;                                   \
      int gc = k0 + 8 * (s ^ (row & 7));                               \
      gload_lds16(Wb + (size_t)row * 1024 + gc, As[bi] + sp * 16);     \
      gload_lds16(Ab + (size_t)row * 1024 + gc, Bs[bi] + sp * 16);     \
    } }

  STAGEG(0, 0);
  for (int t = 0; t < 16; ++t) {
    __syncthreads();
    if (t < 15) STAGEG(t + 1, (t + 1) & 1);
    const char* Ac = As[t & 1];   // W tile (first operand)
    const char* Bc = Bs[t & 1];   // A tile (second operand)
    #pragma unroll
    for (int kk = 0; kk < 2; kk++) {
      bf16x8 wfr[2], afr[4];
      #pragma unroll
      for (int i = 0; i < 2; i++) {
        int row = wf4 * 32 + i * 16 + lo;
        wfr[i] = *(const bf16x8*)(Ac + row * 128 + 16 * ((kk * 4 + hi) ^ (row & 7)));
      }
      #pragma unroll
      for (int j = 0; j < 4; j++) {
        int row = wm2 * 64 + j * 16 + lo;
        afr[j] = *(const bf16x8*)(Bc + row * 128 + 16 * ((kk * 4 + hi) ^ (row & 7)));
      }
      __builtin_amdgcn_s_setprio(1);
      #pragma unroll
      for (int i = 0; i < 2; i++)
        #pragma unroll
        for (int j = 0; j < 4; j++)
          acc[i][j] = MFMA(wfr[i], afr[j], acc[i][j]);
      __builtin_amdgcn_s_setprio(0);
    }
  }
  #undef STAGEG

  #pragma unroll
  for (int i = 0; i < 2; i++) {
    int fl = f0 + wf4 * 32 + i * 16 + hi * 4;
    float4 b4 = *(const float4*)(bias + fl);
    #pragma unroll
    for (int j = 0; j < 4; j++) {
      int m = mt * 128 + wm2 * 64 + j * 16 + lo;
      float4 o;
      o.x = acc[i][j][0] + b4.x;
      o.y = acc[i][j][1] + b4.y;
      o.z = acc[i][j][2] + b4.z;
      o.w = acc[i][j][3] + b4.w;
      *(float4*)(Cout + (size_t)m * 1024 + fl) = o;
    }
  }
}

// ---------------- launch ----------------
extern "C" void kernel_launch(void* const* d_in, const int* in_sizes, int n_in,
                              void* d_out, int out_size, void* d_ws, size_t ws_size,
                              hipStream_t stream) {
  const float* x  = (const float*)d_in[0];
  const float* Wq = (const float*)d_in[1];
  const float* bq = (const float*)d_in[2];
  const float* Wk = (const float*)d_in[3];
  const float* bk = (const float*)d_in[4];
  const float* Wv = (const float*)d_in[5];
  const float* bv = (const float*)d_in[6];
  const float* Wo = (const float*)d_in[7];
  const float* bo = (const float*)d_in[8];
  float* out = (float*)d_out;
  char* ws = (char*)d_ws;

  bf16* xb  = (bf16*)(ws);
  bf16* wqb = (bf16*)(ws + 8388608);
  bf16* wkb = (bf16*)(ws + 10485760);
  bf16* wvb = (bf16*)(ws + 12582912);
  bf16* wob = (bf16*)(ws + 14680064);
  bf16* Qw  = (bf16*)(ws + 16777216);
  bf16* Kw  = (bf16*)(ws + 25165824);
  bf16* Vtw = (bf16*)(ws + 33554432);
  bf16* Ow  = (bf16*)(ws + 41943040);   // total 50331648 B

  k_cvt<<<dim3(2048, 5), 256, 0, stream>>>(x, Wq, Wk, Wv, Wo, xb, wqb, wkb, wvb, wob);
  k_gemm_qkv<<<dim3(32, 24), 256, 0, stream>>>(xb, wqb, wkb, wvb, bq, bk, bv, Qw, Kw, Vtw);
  k_attn<<<dim3(16, 32), 256, 0, stream>>>(Qw, Kw, Vtw, Ow);
  k_gemm_out<<<dim3(32, 8), 512, 0, stream>>>(Ow, wob, bo, out);
}

// Round 13
// 104.411 us; speedup vs baseline: 1.0833x; 1.0113x over previous
//
#include <hip/hip_runtime.h>
#include <hip/hip_bf16.h>
#include <stdint.h>

typedef __bf16 bf16;
typedef __bf16 bf16x8 __attribute__((ext_vector_type(8)));
typedef __bf16 bf16x4 __attribute__((ext_vector_type(4)));
typedef __bf16 bf16x2 __attribute__((ext_vector_type(2)));
typedef float  f32x4  __attribute__((ext_vector_type(4)));
typedef float  f32x16 __attribute__((ext_vector_type(16)));
typedef unsigned int uint;

#define MFMA(a,b,c)   __builtin_amdgcn_mfma_f32_16x16x32_bf16((a),(b),(c),0,0,0)
#define MFMA32(a,b,c) __builtin_amdgcn_mfma_f32_32x32x16_bf16((a),(b),(c),0,0,0)
#define EXP2(x)       __builtin_amdgcn_exp2f(x)

__device__ __forceinline__ void gload_lds16(const void* g, void* lds) {
  __builtin_amdgcn_global_load_lds(
      (const __attribute__((address_space(1))) uint32_t*)g,
      (__attribute__((address_space(3))) uint32_t*)lds, 16, 0, 0);
}

__device__ __forceinline__ uint pk_bf16(float lo, float hi) {
  bf16x2 v; v[0] = (bf16)lo; v[1] = (bf16)hi;
  return __builtin_bit_cast(uint, v);
}

// ---------------- convert fp32 -> bf16 (x + 4 weights) ----------------
__global__ __launch_bounds__(256) void k_cvt(
    const float* __restrict__ x,
    const float* __restrict__ wq, const float* __restrict__ wk,
    const float* __restrict__ wv, const float* __restrict__ wo,
    bf16* __restrict__ xb, bf16* __restrict__ wqb, bf16* __restrict__ wkb,
    bf16* __restrict__ wvb, bf16* __restrict__ wob)
{
  int r = blockIdx.y;
  const float* s; bf16* d; int n;
  switch (r) {
    case 0: s = x;  d = xb;  n = 4194304; break;
    case 1: s = wq; d = wqb; n = 1048576; break;
    case 2: s = wk; d = wkb; n = 1048576; break;
    case 3: s = wv; d = wvb; n = 1048576; break;
    default: s = wo; d = wob; n = 1048576; break;
  }
  int i = (blockIdx.x * 256 + threadIdx.x) * 8;
  if (i >= n) return;
  const float4* sp = (const float4*)(s + i);
  float4 a = sp[0], b = sp[1];
  bf16x8 o;
  o[0]=(bf16)a.x; o[1]=(bf16)a.y; o[2]=(bf16)a.z; o[3]=(bf16)a.w;
  o[4]=(bf16)b.x; o[5]=(bf16)b.y; o[6]=(bf16)b.z; o[7]=(bf16)b.w;
  *(bf16x8*)(d + i) = o;
}

// ---------------- fused QKV projection GEMM (2-phase, BK=32 dbuf) -----------
__global__ __launch_bounds__(256, 2) void k_gemm_qkv(
    const bf16* __restrict__ A,
    const bf16* __restrict__ Wq, const bf16* __restrict__ Wk, const bf16* __restrict__ Wv,
    const float* __restrict__ bq, const float* __restrict__ bk, const float* __restrict__ bv,
    bf16* __restrict__ Qw, bf16* __restrict__ Kw, bf16* __restrict__ Vtw)
{
  __shared__ __align__(16) char As[2][8192];
  __shared__ __align__(16) char Bs[2][8192];
  int tid = threadIdx.x;
  int wv4 = tid >> 6, l = tid & 63, lo = l & 15, hi = l >> 4;
  int f = blockIdx.y * 32 + blockIdx.x;        // 0..767
  int xcd = f & 7, i8 = f >> 3;                // i8: 0..95
  int mt = xcd * 4 + (i8 & 3);                 // 0..31
  int ft = i8 >> 2;                            // 0..23
  int wsel = ft >> 3;
  const bf16* W = (wsel == 0) ? Wq : (wsel == 1) ? Wk : Wv;
  const float* bias = (wsel == 0) ? bq : (wsel == 1) ? bk : bv;
  int f0 = (ft & 7) * 128;
  const bf16* Ab = A + (size_t)mt * 128 * 1024;
  const bf16* Wb = W + (size_t)f0 * 1024;
  const bf16* Pa = (wsel < 2) ? Wb : Ab;   // first operand
  const bf16* Pb = (wsel < 2) ? Ab : Wb;   // second operand
  int wm = wv4 >> 1, wf = wv4 & 1;
  f32x4 acc[4][4];
  #pragma unroll
  for (int i = 0; i < 4; i++)
    #pragma unroll
    for (int j = 0; j < 4; j++) acc[i][j] = (f32x4){0.f, 0.f, 0.f, 0.f};

  #define STAGEG(t, bi) {                                              \
    int k0 = (t) * 32;                                                 \
    _Pragma("unroll")                                                  \
    for (int p = 0; p < 2; p++) {                                      \
      int sp = p * 256 + tid;                                          \
      int row = sp >> 2, s = sp & 3;                                   \
      int gc = k0 + 8 * (s ^ ((row >> 1) & 3));                        \
      gload_lds16(Pa + (size_t)row * 1024 + gc, As[bi] + sp * 16);     \
      gload_lds16(Pb + (size_t)row * 1024 + gc, Bs[bi] + sp * 16);     \
    } }

  STAGEG(0, 0);
  for (int t = 0; t < 32; ++t) {
    __syncthreads();
    if (t < 31) STAGEG(t + 1, (t + 1) & 1);
    const char* Ac = As[t & 1];
    const char* Bc = Bs[t & 1];
    bf16x8 af[4], bfr[4];
    #pragma unroll
    for (int ms = 0; ms < 4; ms++) {
      int row = wm * 64 + ms * 16 + lo;
      af[ms] = *(const bf16x8*)(Ac + row * 64 + 16 * (hi ^ ((row >> 1) & 3)));
    }
    #pragma unroll
    for (int fs = 0; fs < 4; fs++) {
      int row = wf * 64 + fs * 16 + lo;
      bfr[fs] = *(const bf16x8*)(Bc + row * 64 + 16 * (hi ^ ((row >> 1) & 3)));
    }
    __builtin_amdgcn_s_setprio(1);
    #pragma unroll
    for (int ms = 0; ms < 4; ms++)
      #pragma unroll
      for (int fs = 0; fs < 4; fs++)
        acc[ms][fs] = MFMA(af[ms], bfr[fs], acc[ms][fs]);
    __builtin_amdgcn_s_setprio(0);
  }
  #undef STAGEG

  if (wsel < 2) {
    bf16* Outp = (wsel == 0) ? Qw : Kw;
    float qs = (wsel == 0) ? 0.0450842199527801f : 1.0f;
    #pragma unroll
    for (int ms = 0; ms < 4; ms++) {
      int fl = f0 + wm * 64 + ms * 16 + hi * 4;
      int h = fl >> 6, dd = fl & 63;
      float4 b4 = *(const float4*)(bias + fl);
      #pragma unroll
      for (int fs = 0; fs < 4; fs++) {
        int m = mt * 128 + wf * 64 + fs * 16 + lo;
        int b = m >> 11, nn = m & 2047;
        bf16x4 w;
        #pragma unroll
        for (int r = 0; r < 4; r++)
          w[r] = (bf16)((acc[ms][fs][r] + ((const float*)&b4)[r]) * qs);
        *(bf16x4*)(Outp + (((size_t)(b * 16 + h) * 2048 + nn) * 64) + dd) = w;
      }
    }
  } else {
    #pragma unroll
    for (int fs = 0; fs < 4; fs++) {
      int fl = f0 + wf * 64 + fs * 16 + lo;
      int h = fl >> 6, dd = fl & 63;
      float bb = bias[fl];
      #pragma unroll
      for (int ms = 0; ms < 4; ms++) {
        int m = mt * 128 + wm * 64 + ms * 16 + hi * 4;
        int b = m >> 11, nn = m & 2047;
        bf16x4 w;
        #pragma unroll
        for (int r = 0; r < 4; r++) w[r] = (bf16)(acc[ms][fs][r] + bb);
        *(bf16x4*)(Vtw + (((size_t)(b * 16 + h) * 64 + dd) * 2048) + nn) = w;
      }
    }
  }
}

// ---------------- flash attention v8: split-parity, QBLK=64/wave ------------
// 4 waves = (q-half, k-parity); each wave: 64 q x 16 k-tiles. Each K/V tile
// read by 2 waves (not 4) -> LDS read traffic halved. 4 LDS buffers,
// 1 barrier/epoch. Partial (O,l) combined across k-parity pairs via LDS.
__global__ __launch_bounds__(256, 2) void k_attn(
    const bf16* __restrict__ Q, const bf16* __restrict__ K,
    const bf16* __restrict__ Vt, bf16* __restrict__ O)
{
  __shared__ __align__(16) char Ks[4][8192];
  __shared__ __align__(16) char Vs[4][8192];
  int tid = threadIdx.x;
  int wid = tid >> 6, l = tid & 63;
  int lq = l & 31, hi1 = l >> 5;
  int qhalf = wid >> 1, kpar = wid & 1;
  int f = blockIdx.y * 16 + blockIdx.x;        // 0..511
  int xcd = f & 7, i8 = f >> 3;                // i8: 0..63
  int bh = xcd * 4 + (i8 & 3);                 // 0..31
  int qt = i8 >> 2;                            // 0..15
  int q0 = qt * 128 + qhalf * 64;
  const bf16* Kb = K + (size_t)bh * 2048 * 64;
  const bf16* Vb = Vt + (size_t)bh * 64 * 2048;

  // Q fragments for this wave's 64 q-rows (2 groups of 32)
  bf16x8 qf0[4], qf1[4];
  const bf16* Qb = Q + ((size_t)bh * 2048 + q0) * 64 + hi1 * 8;
  #pragma unroll
  for (int c = 0; c < 4; c++) {
    qf0[c] = *(const bf16x8*)(Qb + (size_t)lq * 64 + 16 * c);
    qf1[c] = *(const bf16x8*)(Qb + (size_t)(lq + 32) * 64 + 16 * c);
  }

  f32x16 o00, o01, o10, o11, zz;
  #pragma unroll
  for (int r = 0; r < 16; r++) { zz[r] = 0.f; o00[r] = 0.f; o01[r] = 0.f; o10[r] = 0.f; o11[r] = 0.f; }
  float ls0 = 0.f, ls1 = 0.f;

  int srow = tid >> 3, slot = tid & 7;
  int swz = 16 * (slot ^ (srow & 7));
  int swk = lq & 7;
  uint4 xk0, xk1, xv0, xv1;    // staging set X (even tiles)
  uint4 yk0, yk1, yv0, yv1;    // staging set Y (odd tiles)
  #define STAGEX(t) {                                                          \
    xk0 = *(const uint4*)(Kb + (size_t)((t)*64 + srow) * 64 + slot * 8);       \
    xk1 = *(const uint4*)(Kb + (size_t)((t)*64 + srow + 32) * 64 + slot * 8);  \
    xv0 = *(const uint4*)(Vb + (size_t)srow * 2048 + (t)*64 + slot * 8);       \
    xv1 = *(const uint4*)(Vb + (size_t)(srow + 32) * 2048 + (t)*64 + slot * 8); }
  #define STAGEY(t) {                                                          \
    yk0 = *(const uint4*)(Kb + (size_t)((t)*64 + srow) * 64 + slot * 8);       \
    yk1 = *(const uint4*)(Kb + (size_t)((t)*64 + srow + 32) * 64 + slot * 8);  \
    yv0 = *(const uint4*)(Vb + (size_t)srow * 2048 + (t)*64 + slot * 8);       \
    yv1 = *(const uint4*)(Vb + (size_t)(srow + 32) * 2048 + (t)*64 + slot * 8); }
  #define WRX(bi) {                                     \
    *(uint4*)(Ks[bi] + srow * 128 + swz)        = xk0;  \
    *(uint4*)(Ks[bi] + (srow + 32) * 128 + swz) = xk1;  \
    *(uint4*)(Vs[bi] + srow * 128 + swz)        = xv0;  \
    *(uint4*)(Vs[bi] + (srow + 32) * 128 + swz) = xv1; }
  #define WRY(bi) {                                     \
    *(uint4*)(Ks[bi] + srow * 128 + swz)        = yk0;  \
    *(uint4*)(Ks[bi] + (srow + 32) * 128 + swz) = yk1;  \
    *(uint4*)(Vs[bi] + srow * 128 + swz)        = yv0;  \
    *(uint4*)(Vs[bi] + (srow + 32) * 128 + swz) = yv1; }
  #define EXPSUM(S, T0, T1, T2, T3)                     \
    _Pragma("unroll")                                   \
    for (int r = 0; r < 16; r += 4) {                   \
      S[r]   = EXP2(S[r]);   T0 += S[r];                \
      S[r+1] = EXP2(S[r+1]); T1 += S[r+1];              \
      S[r+2] = EXP2(S[r+2]); T2 += S[r+2];              \
      S[r+3] = EXP2(S[r+3]); T3 += S[r+3];              \
    }
  #define PACK(dst, plo, phi)                                                \
    _Pragma("unroll")                                                        \
    for (int m = 0; m < 2; m++) {                                            \
      uint a0 = pk_bf16(plo[8*m+0], plo[8*m+1]);                             \
      uint b0 = pk_bf16(plo[8*m+4], plo[8*m+5]);                             \
      asm volatile("v_permlane32_swap_b32 %0, %1" : "+v"(a0), "+v"(b0));     \
      uint a1 = pk_bf16(plo[8*m+2], plo[8*m+3]);                             \
      uint b1 = pk_bf16(plo[8*m+6], plo[8*m+7]);                             \
      asm volatile("v_permlane32_swap_b32 %0, %1" : "+v"(a1), "+v"(b1));     \
      dst[m] = (uint4){a0, a1, b0, b1};                                      \
      uint c0 = pk_bf16(phi[8*m+0], phi[8*m+1]);                             \
      uint d0 = pk_bf16(phi[8*m+4], phi[8*m+5]);                             \
      asm volatile("v_permlane32_swap_b32 %0, %1" : "+v"(c0), "+v"(d0));     \
      uint c1 = pk_bf16(phi[8*m+2], phi[8*m+3]);                             \
      uint d1 = pk_bf16(phi[8*m+6], phi[8*m+7]);                             \
      asm volatile("v_permlane32_swap_b32 %0, %1" : "+v"(c1), "+v"(d1));     \
      dst[2+m] = (uint4){c0, c1, d0, d1};                                    \
    }

  // prologue: tiles 0,1 -> bufs 0,2; tiles 2,3 staged in regs
  STAGEX(0); STAGEY(1);
  WRX(0); WRY(2);
  STAGEX(2); STAGEY(3);

  for (int e = 0; e < 16; ++e) {
    __syncthreads();
    if (e < 15) {
      WRX((e + 1) & 1);          // tile 2e+2 -> even-family buffer
      WRY(2 + ((e + 1) & 1));    // tile 2e+3 -> odd-family buffer
    }
    int bi = kpar ? (2 + (e & 1)) : (e & 1);
    const char* Kc = (const char*)Ks + (size_t)bi * 8192;
    const char* Vc = (const char*)Vs + (size_t)bi * 8192;

    // QK^T: 4 32x32 S-tiles (2 q-groups x 2 k-halves)
    bf16x8 kf0[4], kf1[4];
    #pragma unroll
    for (int c = 0; c < 4; c++) {
      kf0[c] = *(const bf16x8*)(Kc + lq * 128 + 16 * ((2*c + hi1) ^ swk));
      kf1[c] = *(const bf16x8*)(Kc + (32 + lq) * 128 + 16 * ((2*c + hi1) ^ swk));
    }
    __builtin_amdgcn_s_setprio(1);
    f32x16 s00 = MFMA32(kf0[0], qf0[0], zz);
    f32x16 s01 = MFMA32(kf1[0], qf0[0], zz);
    f32x16 s10 = MFMA32(kf0[0], qf1[0], zz);
    f32x16 s11 = MFMA32(kf1[0], qf1[0], zz);
    #pragma unroll
    for (int c = 1; c < 4; c++) {
      s00 = MFMA32(kf0[c], qf0[c], s00);
      s01 = MFMA32(kf1[c], qf0[c], s01);
      s10 = MFMA32(kf0[c], qf1[c], s10);
      s11 = MFMA32(kf1[c], qf1[c], s11);
    }
    __builtin_amdgcn_s_setprio(0);

    // max-free softmax
    float t0 = 0.f, t1 = 0.f, t2 = 0.f, t3 = 0.f;
    float u0 = 0.f, u1 = 0.f, u2 = 0.f, u3 = 0.f;
    EXPSUM(s00, t0, t1, t2, t3);
    EXPSUM(s01, t0, t1, t2, t3);
    EXPSUM(s10, u0, u1, u2, u3);
    EXPSUM(s11, u0, u1, u2, u3);
    ls0 += (t0 + t1) + (t2 + t3);
    ls1 += (u0 + u1) + (u2 + u3);

    uint4 pf0[4], pf1[4];
    PACK(pf0, s00, s01);
    PACK(pf1, s10, s11);

    // PV: V fragments read once, used by both q-groups
    __builtin_amdgcn_s_setprio(1);
    #pragma unroll
    for (int c = 0; c < 4; c++) {
      bf16x8 vf0 = *(const bf16x8*)(Vc + lq * 128 + 16 * ((2*c + hi1) ^ swk));
      bf16x8 vf1 = *(const bf16x8*)(Vc + (32 + lq) * 128 + 16 * ((2*c + hi1) ^ swk));
      bf16x8 p0b = __builtin_bit_cast(bf16x8, pf0[c]);
      bf16x8 p1b = __builtin_bit_cast(bf16x8, pf1[c]);
      o00 = MFMA32(vf0, p0b, o00);
      o01 = MFMA32(vf1, p0b, o01);
      o10 = MFMA32(vf0, p1b, o10);
      o11 = MFMA32(vf1, p1b, o11);
    }
    __builtin_amdgcn_s_setprio(0);

    if (e < 14) { STAGEX(2 * e + 4); STAGEY(2 * e + 5); }
  }
  #undef STAGEX
  #undef STAGEY
  #undef WRX
  #undef WRY

  // ---- combine k-parity partners via LDS scratch ----
  __syncthreads();
  float* sc = (float*)(qhalf ? (char*)Vs : (char*)Ks) + 68 * l;
  if (kpar == 1) {
    #pragma unroll
    for (int g = 0; g < 4; g++) {
      *(f32x4*)(sc + 4*g)      = (f32x4){o00[4*g], o00[4*g+1], o00[4*g+2], o00[4*g+3]};
      *(f32x4*)(sc + 16 + 4*g) = (f32x4){o01[4*g], o01[4*g+1], o01[4*g+2], o01[4*g+3]};
      *(f32x4*)(sc + 32 + 4*g) = (f32x4){o10[4*g], o10[4*g+1], o10[4*g+2], o10[4*g+3]};
      *(f32x4*)(sc + 48 + 4*g) = (f32x4){o11[4*g], o11[4*g+1], o11[4*g+2], o11[4*g+3]};
    }
    sc[64] = ls0; sc[65] = ls1;
  }
  __syncthreads();
  if (kpar == 0) {
    #pragma unroll
    for (int g = 0; g < 4; g++) {
      f32x4 a0 = *(const f32x4*)(sc + 4*g);
      f32x4 a1 = *(const f32x4*)(sc + 16 + 4*g);
      f32x4 a2 = *(const f32x4*)(sc + 32 + 4*g);
      f32x4 a3 = *(const f32x4*)(sc + 48 + 4*g);
      #pragma unroll
      for (int j = 0; j < 4; j++) {
        o00[4*g+j] += a0[j];
        o01[4*g+j] += a1[j];
        o10[4*g+j] += a2[j];
        o11[4*g+j] += a3[j];
      }
    }
    ls0 += sc[64]; ls1 += sc[65];
    float lA = ls0 + __shfl_xor(ls0, 32);
    float lB = ls1 + __shfl_xor(ls1, 32);
    float inv0 = 1.0f / lA, inv1 = 1.0f / lB;
    int b = bh >> 4, h = bh & 15;
    bf16* Ob0 = O + ((size_t)(b * 2048 + q0 + lq)) * 1024 + h * 64 + hi1 * 4;
    bf16* Ob1 = O + ((size_t)(b * 2048 + q0 + 32 + lq)) * 1024 + h * 64 + hi1 * 4;
    #pragma unroll
    for (int g = 0; g < 4; g++) {
      bf16x4 w0, w1, w2, w3;
      #pragma unroll
      for (int j = 0; j < 4; j++) {
        w0[j] = (bf16)(o00[4*g+j] * inv0);
        w1[j] = (bf16)(o01[4*g+j] * inv0);
        w2[j] = (bf16)(o10[4*g+j] * inv1);
        w3[j] = (bf16)(o11[4*g+j] * inv1);
      }
      *(bf16x4*)(Ob0 + g * 8)      = w0;
      *(bf16x4*)(Ob0 + 32 + g * 8) = w1;
      *(bf16x4*)(Ob1 + g * 8)      = w2;
      *(bf16x4*)(Ob1 + 32 + g * 8) = w3;
    }
  }
}

// ---------------- output projection GEMM (2-phase, 512 thr, W-first) --------
__global__ __launch_bounds__(512, 1) void k_gemm_out(
    const bf16* __restrict__ A,      // O [4096][1024] bf16
    const bf16* __restrict__ W,      // Wo bf16 [1024][1024]
    const float* __restrict__ bias,  // bo
    float* __restrict__ Cout)        // [4096][1024] fp32
{
  __shared__ __align__(16) char As[2][16384];
  __shared__ __align__(16) char Bs[2][16384];
  int tid = threadIdx.x;
  int wid = tid >> 6, l = tid & 63, lo = l & 15, hi = l >> 4;
  int f = blockIdx.y * 32 + blockIdx.x;        // 0..255
  int xcd = f & 7, i8 = f >> 3;                // i8: 0..31
  int mt = xcd * 4 + (i8 & 3);                 // 0..31
  int f0 = (i8 >> 2) * 128;                    // 0..7 tiles
  const bf16* Ab = A + (size_t)mt * 128 * 1024;
  const bf16* Wb = W + (size_t)f0 * 1024;
  int wm2 = wid >> 2, wf4 = wid & 3;   // 2M x 4F; per-wave out 64m x 32f
  f32x4 acc[2][4];                     // [f-sub][m-sub]
  #pragma unroll
  for (int i = 0; i < 2; i++)
    #pragma unroll
    for (int j = 0; j < 4; j++) acc[i][j] = (f32x4){0.f, 0.f, 0.f, 0.f};

  #define STAGEG(t, bi) {                                              \
    int k0 = (t) * 64;                                                 \
    _Pragma("unroll")                                                  \
    for (int p = 0; p < 2; p++) {                                      \
      int sp = p * 512 + tid;                                          \
      int row = sp >> 3, s = sp & 7;                                   \
      int gc = k0 + 8 * (s ^ (row & 7));                               \
      gload_lds16(Wb + (size_t)row * 1024 + gc, As[bi] + sp * 16);     \
      gload_lds16(Ab + (size_t)row * 1024 + gc, Bs[bi] + sp * 16);     \
    } }

  STAGEG(0, 0);
  for (int t = 0; t < 16; ++t) {
    __syncthreads();
    if (t < 15) STAGEG(t + 1, (t + 1) & 1);
    const char* Ac = As[t & 1];   // W tile (first operand)
    const char* Bc = Bs[t & 1];   // A tile (second operand)
    #pragma unroll
    for (int kk = 0; kk < 2; kk++) {
      bf16x8 wfr[2], afr[4];
      #pragma unroll
      for (int i = 0; i < 2; i++) {
        int row = wf4 * 32 + i * 16 + lo;
        wfr[i] = *(const bf16x8*)(Ac + row * 128 + 16 * ((kk * 4 + hi) ^ (row & 7)));
      }
      #pragma unroll
      for (int j = 0; j < 4; j++) {
        int row = wm2 * 64 + j * 16 + lo;
        afr[j] = *(const bf16x8*)(Bc + row * 128 + 16 * ((kk * 4 + hi) ^ (row & 7)));
      }
      __builtin_amdgcn_s_setprio(1);
      #pragma unroll
      for (int i = 0; i < 2; i++)
        #pragma unroll
        for (int j = 0; j < 4; j++)
          acc[i][j] = MFMA(wfr[i], afr[j], acc[i][j]);
      __builtin_amdgcn_s_setprio(0);
    }
  }
  #undef STAGEG

  #pragma unroll
  for (int i = 0; i < 2; i++) {
    int fl = f0 + wf4 * 32 + i * 16 + hi * 4;
    float4 b4 = *(const float4*)(bias + fl);
    #pragma unroll
    for (int j = 0; j < 4; j++) {
      int m = mt * 128 + wm2 * 64 + j * 16 + lo;
      float4 o;
      o.x = acc[i][j][0] + b4.x;
      o.y = acc[i][j][1] + b4.y;
      o.z = acc[i][j][2] + b4.z;
      o.w = acc[i][j][3] + b4.w;
      *(float4*)(Cout + (size_t)m * 1024 + fl) = o;
    }
  }
}

// ---------------- launch ----------------
extern "C" void kernel_launch(void* const* d_in, const int* in_sizes, int n_in,
                              void* d_out, int out_size, void* d_ws, size_t ws_size,
                              hipStream_t stream) {
  const float* x  = (const float*)d_in[0];
  const float* Wq = (const float*)d_in[1];
  const float* bq = (const float*)d_in[2];
  const float* Wk = (const float*)d_in[3];
  const float* bk = (const float*)d_in[4];
  const float* Wv = (const float*)d_in[5];
  const float* bv = (const float*)d_in[6];
  const float* Wo = (const float*)d_in[7];
  const float* bo = (const float*)d_in[8];
  float* out = (float*)d_out;
  char* ws = (char*)d_ws;

  bf16* xb  = (bf16*)(ws);
  bf16* wqb = (bf16*)(ws + 8388608);
  bf16* wkb = (bf16*)(ws + 10485760);
  bf16* wvb = (bf16*)(ws + 12582912);
  bf16* wob = (bf16*)(ws + 14680064);
  bf16* Qw  = (bf16*)(ws + 16777216);
  bf16* Kw  = (bf16*)(ws + 25165824);
  bf16* Vtw = (bf16*)(ws + 33554432);
  bf16* Ow  = (bf16*)(ws + 41943040);   // total 50331648 B

  k_cvt<<<dim3(2048, 5), 256, 0, stream>>>(x, Wq, Wk, Wv, Wo, xb, wqb, wkb, wvb, wob);
  k_gemm_qkv<<<dim3(32, 24), 256, 0, stream>>>(xb, wqb, wkb, wvb, bq, bk, bv, Qw, Kw, Vtw);
  k_attn<<<dim3(16, 32), 256, 0, stream>>>(Qw, Kw, Vtw, Ow);
  k_gemm_out<<<dim3(32, 8), 512, 0, stream>>>(Ow, wob, bo, out);
}